// Round 1
// baseline (542.925 us; speedup 1.0000x reference)
//
#include <hip/hip_runtime.h>
#include <math.h>

#define LQ 22223
#define NH 8
#define NL 4
#define NP 4
#define CDIM 256

// ---------------------------------------------------------------------------
// Tiled fp32 GEMM: C[M,N] = A[M,K] @ B[K,N] + bias[N]
// BM=BN=64, BK=16, 256 threads, 4x4 microtile per thread.
// K must be a multiple of 16 (always 256 here). N must be a multiple of 64.
// ---------------------------------------------------------------------------
__global__ __launch_bounds__(256) void gemm_bias_f32(
    const float* __restrict__ A, const float* __restrict__ B,
    const float* __restrict__ bias, float* __restrict__ C,
    int M, int N, int K)
{
    __shared__ float As[16][64];   // As[k][m]
    __shared__ float Bs[16][64];   // Bs[k][n]

    const int tid = threadIdx.x;
    const int tx = tid & 15;       // column group 0..15
    const int ty = tid >> 4;       // row group 0..15
    const int bm = blockIdx.y * 64;
    const int bn = blockIdx.x * 64;

    // loader coords
    const int am  = tid >> 2;      // 0..63  (A row within tile)
    const int ak4 = tid & 3;       // 0..3   (A k-float4 within BK)
    const int bk  = tid >> 4;      // 0..15  (B k within BK)
    const int bc4 = tid & 15;      // 0..15  (B col-float4 within BN)

    float acc[4][4] = {};

    for (int k0 = 0; k0 < K; k0 += 16) {
        float4 af = make_float4(0.f, 0.f, 0.f, 0.f);
        const int arow = bm + am;
        if (arow < M)
            af = *reinterpret_cast<const float4*>(A + (size_t)arow * K + k0 + ak4 * 4);
        const float4 bf = *reinterpret_cast<const float4*>(
            B + (size_t)(k0 + bk) * N + bn + bc4 * 4);

        __syncthreads();   // protect previous iteration's reads
        As[ak4 * 4 + 0][am] = af.x;
        As[ak4 * 4 + 1][am] = af.y;
        As[ak4 * 4 + 2][am] = af.z;
        As[ak4 * 4 + 3][am] = af.w;
        *reinterpret_cast<float4*>(&Bs[bk][bc4 * 4]) = bf;
        __syncthreads();

        #pragma unroll
        for (int kk = 0; kk < 16; ++kk) {
            const float4 a4 = *reinterpret_cast<const float4*>(&As[kk][ty * 4]);
            const float4 b4 = *reinterpret_cast<const float4*>(&Bs[kk][tx * 4]);
            const float a[4] = {a4.x, a4.y, a4.z, a4.w};
            const float b[4] = {b4.x, b4.y, b4.z, b4.w};
            #pragma unroll
            for (int i = 0; i < 4; ++i)
                #pragma unroll
                for (int j = 0; j < 4; ++j)
                    acc[i][j] += a[i] * b[j];
        }
    }

    const int col = bn + tx * 4;
    const float4 bsv = *reinterpret_cast<const float4*>(bias + col);
    #pragma unroll
    for (int i = 0; i < 4; ++i) {
        const int row = bm + ty * 4 + i;
        if (row < M) {
            const float4 o = make_float4(acc[i][0] + bsv.x, acc[i][1] + bsv.y,
                                         acc[i][2] + bsv.z, acc[i][3] + bsv.w);
            *reinterpret_cast<float4*>(C + (size_t)row * N + col) = o;
        }
    }
}

// ---------------------------------------------------------------------------
// In-place softmax over rows of 16 (one thread per (q,h) row)
// ---------------------------------------------------------------------------
__global__ __launch_bounds__(256) void softmax16(float* __restrict__ logits, int rows)
{
    const int r = blockIdx.x * 256 + threadIdx.x;
    if (r >= rows) return;
    float4* p = reinterpret_cast<float4*>(logits + (size_t)r * 16);
    float v[16];
    #pragma unroll
    for (int i = 0; i < 4; ++i) {
        const float4 f = p[i];
        v[i * 4 + 0] = f.x; v[i * 4 + 1] = f.y; v[i * 4 + 2] = f.z; v[i * 4 + 3] = f.w;
    }
    float m = v[0];
    #pragma unroll
    for (int i = 1; i < 16; ++i) m = fmaxf(m, v[i]);
    float s = 0.f;
    #pragma unroll
    for (int i = 0; i < 16; ++i) { v[i] = expf(v[i] - m); s += v[i]; }
    const float inv = 1.f / s;
    #pragma unroll
    for (int i = 0; i < 4; ++i)
        p[i] = make_float4(v[i * 4 + 0] * inv, v[i * 4 + 1] * inv,
                           v[i * 4 + 2] * inv, v[i * 4 + 3] * inv);
}

// ---------------------------------------------------------------------------
// Multi-scale deformable sampling.
// One thread per (q, h, d): gid = q*256 + h*32 + d.
// 32 consecutive lanes share (q,h) -> 128B coalesced gathers per corner.
// ---------------------------------------------------------------------------
__global__ __launch_bounds__(256) void msda_sample(
    const float* __restrict__ v, const float* __restrict__ off,
    const float* __restrict__ attnw, const float* __restrict__ ref,
    float* __restrict__ outp)
{
    const int gid = blockIdx.x * 256 + threadIdx.x;
    const int d = gid & 31;
    const int h = (gid >> 5) & 7;
    const int q = gid >> 8;
    if (q >= LQ) return;

    const int   Hs[4] = {100, 50, 25, 13};
    const int   Ws[4] = {167, 84, 42, 21};
    const int   starts[4] = {0, 16700, 20900, 21950};

    const float* offq = off + (size_t)q * CDIM + h * 32;   // 16 points * 2
    const float* aw   = attnw + (size_t)q * (NH * 16) + h * 16;
    const float* refq = ref + (size_t)q * (NL * 4);

    float acc = 0.f;

    #pragma unroll
    for (int l = 0; l < 4; ++l) {
        const float cx = refq[l * 4 + 0];
        const float cy = refq[l * 4 + 1];
        const float rw = refq[l * 4 + 2];
        const float rh = refq[l * 4 + 3];
        const int   W  = Ws[l];
        const int   H  = Hs[l];
        const float fW = (float)W;
        const float fH = (float)H;
        const float* vl = v + (size_t)starts[l] * CDIM + h * 32 + d;

        #pragma unroll
        for (int p = 0; p < 4; ++p) {
            const float ox  = offq[l * 8 + p * 2 + 0];
            const float oy  = offq[l * 8 + p * 2 + 1];
            const float wgt = aw[l * 4 + p];

            // loc = ref_cxcy + off/NP * ref_wh * 0.5 ; grid = 2*loc - 1
            const float lx = cx + ((ox * 0.25f) * rw) * 0.5f;
            const float ly = cy + ((oy * 0.25f) * rh) * 0.5f;
            const float gx = 2.f * lx - 1.f;
            const float gy = 2.f * ly - 1.f;
            const float x = (gx + 1.f) * 0.5f * fW - 0.5f;
            const float y = (gy + 1.f) * 0.5f * fH - 0.5f;

            const float x0f = floorf(x);
            const float y0f = floorf(y);
            const int x0 = (int)x0f;
            const int y0 = (int)y0f;
            const float wx1 = x - x0f, wy1 = y - y0f;
            const float wx0 = 1.f - wx1, wy0 = 1.f - wy1;

            const bool xv0 = (x0 >= 0) && (x0 < W);
            const bool xv1 = (x0 + 1 >= 0) && (x0 + 1 < W);
            const bool yv0 = (y0 >= 0) && (y0 < H);
            const bool yv1 = (y0 + 1 >= 0) && (y0 + 1 < H);

            float s = 0.f;
            if (yv0) {
                const float* row0 = vl + (size_t)(y0 * W) * CDIM;
                if (xv0) s += row0[(size_t)x0 * CDIM] * (wy0 * wx0);
                if (xv1) s += row0[(size_t)(x0 + 1) * CDIM] * (wy0 * wx1);
            }
            if (yv1) {
                const float* row1 = vl + (size_t)((y0 + 1) * W) * CDIM;
                if (xv0) s += row1[(size_t)x0 * CDIM] * (wy1 * wx0);
                if (xv1) s += row1[(size_t)(x0 + 1) * CDIM] * (wy1 * wx1);
            }
            acc += wgt * s;
        }
    }
    outp[gid] = acc;
}

// ---------------------------------------------------------------------------
extern "C" void kernel_launch(void* const* d_in, const int* in_sizes, int n_in,
                              void* d_out, int out_size, void* d_ws, size_t ws_size,
                              hipStream_t stream)
{
    const float* query  = (const float*)d_in[0];
    const float* ref    = (const float*)d_in[1];
    const float* value  = (const float*)d_in[2];
    const float* W_off  = (const float*)d_in[3];
    const float* b_off  = (const float*)d_in[4];
    const float* W_attn = (const float*)d_in[5];
    const float* b_attn = (const float*)d_in[6];
    const float* W_val  = (const float*)d_in[7];
    const float* b_val  = (const float*)d_in[8];
    const float* W_out  = (const float*)d_in[9];
    const float* b_out  = (const float*)d_in[10];
    float* out = (float*)d_out;

    float* ws   = (float*)d_ws;
    float* v    = ws;                               // LQ*256
    float* off  = v + (size_t)LQ * CDIM;            // LQ*256
    float* attn = off + (size_t)LQ * CDIM;          // LQ*128
    float* outp = attn + (size_t)LQ * (NH * 16);    // LQ*256

    const int mblk = (LQ + 63) / 64;   // 348

    // 1. v = value @ W_val + b_val
    gemm_bias_f32<<<dim3(CDIM / 64, mblk), 256, 0, stream>>>(
        value, W_val, b_val, v, LQ, CDIM, CDIM);
    // 2. off = query @ W_off + b_off
    gemm_bias_f32<<<dim3(CDIM / 64, mblk), 256, 0, stream>>>(
        query, W_off, b_off, off, LQ, CDIM, CDIM);
    // 3. attn logits = query @ W_attn + b_attn
    gemm_bias_f32<<<dim3(128 / 64, mblk), 256, 0, stream>>>(
        query, W_attn, b_attn, attn, LQ, 128, CDIM);
    // 4. softmax over 16 per (q,h)
    softmax16<<<(LQ * NH + 255) / 256, 256, 0, stream>>>(attn, LQ * NH);
    // 5. deformable bilinear sampling -> outp
    msda_sample<<<LQ, 256, 0, stream>>>(v, off, attn, ref, outp);
    // 6. out = outp @ W_out + b_out
    gemm_bias_f32<<<dim3(CDIM / 64, mblk), 256, 0, stream>>>(
        outp, W_out, b_out, out, LQ, CDIM, CDIM);
}

// Round 2
// 374.044 us; speedup vs baseline: 1.4515x; 1.4515x over previous
//
#include <hip/hip_runtime.h>
#include <math.h>

#define LQ 22223
#define NH 8
#define NL 4
#define NP 4
#define CDIM 256

typedef __attribute__((ext_vector_type(8))) short short8;
typedef __attribute__((ext_vector_type(4))) float f32x4;

__device__ __forceinline__ ushort f2bf(float f) {
    union { float f; unsigned u; } c; c.f = f;
    unsigned u = c.u;
    return (ushort)((u + 0x7fffu + ((u >> 16) & 1u)) >> 16);   // RNE
}

// ---------------------------------------------------------------------------
// Convert query & value fp32 -> bf16 (8 elems/thread)
// ---------------------------------------------------------------------------
__global__ __launch_bounds__(256) void convert_act(
    const float4* __restrict__ q, const float4* __restrict__ v,
    ushort* __restrict__ qb, ushort* __restrict__ vb, int n8each)
{
    int i = blockIdx.x * 256 + threadIdx.x;
    const float4* src; ushort* dst; int j;
    if (i < n8each) { src = q; dst = qb; j = i; }
    else if (i < 2 * n8each) { src = v; dst = vb; j = i - n8each; }
    else return;
    const float4 a = src[2 * j];
    const float4 b = src[2 * j + 1];
    short8 o;
    o[0] = (short)f2bf(a.x); o[1] = (short)f2bf(a.y);
    o[2] = (short)f2bf(a.z); o[3] = (short)f2bf(a.w);
    o[4] = (short)f2bf(b.x); o[5] = (short)f2bf(b.y);
    o[6] = (short)f2bf(b.z); o[7] = (short)f2bf(b.w);
    *reinterpret_cast<short8*>(dst + 8 * j) = o;
}

// ---------------------------------------------------------------------------
// Transpose + convert the 4 weight matrices: W[K=256][N] fp32 -> Wt[N][K] bf16
// segments: W_val (N=256), W_off (N=256), W_out (N=256), W_attn (N=128)
// ---------------------------------------------------------------------------
__global__ __launch_bounds__(256) void convert_wt(
    const float* __restrict__ Wv, const float* __restrict__ Wo,
    const float* __restrict__ Wu, const float* __restrict__ Wa,
    ushort* __restrict__ Tv, ushort* __restrict__ To,
    ushort* __restrict__ Tu, ushort* __restrict__ Ta)
{
    int idx = blockIdx.x * 256 + threadIdx.x;   // 0 .. 229375
    const float* W; ushort* T; int N; int local;
    if      (idx < 65536)  { W = Wv; T = Tv; N = 256; local = idx; }
    else if (idx < 131072) { W = Wo; T = To; N = 256; local = idx - 65536; }
    else if (idx < 196608) { W = Wu; T = Tu; N = 256; local = idx - 131072; }
    else if (idx < 229376) { W = Wa; T = Ta; N = 128; local = idx - 196608; }
    else return;
    int k = local & 255;
    int n = local >> 8;
    T[n * 256 + k] = f2bf(W[k * N + n]);
}

// ---------------------------------------------------------------------------
// bf16 MFMA GEMM: C[M,N] = A[M,256] @ Bt[N,256]^T + bias[N]   (fp32 out)
// 64x64 tile, BK=32, 256 threads = 4 waves, each wave 16 rows x 64 cols.
// LDS rows padded to 40 bf16 (80 B) -> 2-way bank aliasing only (free).
// ---------------------------------------------------------------------------
__global__ __launch_bounds__(256) void gemm_bf16(
    const ushort* __restrict__ A, const ushort* __restrict__ Bt,
    const float* __restrict__ bias, float* __restrict__ C,
    int M, int N)
{
    const int K = 256;
    __shared__ ushort As[64 * 40];
    __shared__ ushort Bs[64 * 40];

    const int tid = threadIdx.x;
    const int w = tid >> 6;          // wave 0..3
    const int l = tid & 63;          // lane
    const int bm = blockIdx.y * 64;
    const int bn = blockIdx.x * 64;

    const int r = tid >> 2;          // staging row 0..63
    const int c = tid & 3;           // staging 16B chunk 0..3

    const int m_l  = (w << 4) + (l & 15);   // A-frag local row
    const int koff = (l >> 4) << 3;         // frag k offset 0/8/16/24

    f32x4 acc[4] = {};

    for (int k0 = 0; k0 < K; k0 += 32) {
        short8 av = {0, 0, 0, 0, 0, 0, 0, 0};
        if (bm + r < M)
            av = *reinterpret_cast<const short8*>(A + (size_t)(bm + r) * K + k0 + c * 8);
        const short8 bv = *reinterpret_cast<const short8*>(
            Bt + (size_t)(bn + r) * K + k0 + c * 8);

        __syncthreads();
        *reinterpret_cast<short8*>(&As[r * 40 + c * 8]) = av;
        *reinterpret_cast<short8*>(&Bs[r * 40 + c * 8]) = bv;
        __syncthreads();

        const short8 af = *reinterpret_cast<const short8*>(&As[m_l * 40 + koff]);
        #pragma unroll
        for (int t = 0; t < 4; ++t) {
            const short8 bf = *reinterpret_cast<const short8*>(
                &Bs[(t * 16 + (l & 15)) * 40 + koff]);
            acc[t] = __builtin_amdgcn_mfma_f32_16x16x32_bf16(af, bf, acc[t], 0, 0, 0);
        }
    }

    // C/D layout: col = lane&15, row = (lane>>4)*4 + i
    const int row0 = bm + (w << 4) + ((l >> 4) << 2);
    #pragma unroll
    for (int t = 0; t < 4; ++t) {
        const int col = bn + t * 16 + (l & 15);
        const float bs = bias[col];
        #pragma unroll
        for (int i = 0; i < 4; ++i) {
            const int row = row0 + i;
            if (row < M) C[(size_t)row * N + col] = acc[t][i] + bs;
        }
    }
}

// ---------------------------------------------------------------------------
// In-place softmax over rows of 16 (one thread per (q,h) row)
// ---------------------------------------------------------------------------
__global__ __launch_bounds__(256) void softmax16(float* __restrict__ logits, int rows)
{
    const int r = blockIdx.x * 256 + threadIdx.x;
    if (r >= rows) return;
    float4* p = reinterpret_cast<float4*>(logits + (size_t)r * 16);
    float v[16];
    #pragma unroll
    for (int i = 0; i < 4; ++i) {
        const float4 f = p[i];
        v[i * 4 + 0] = f.x; v[i * 4 + 1] = f.y; v[i * 4 + 2] = f.z; v[i * 4 + 3] = f.w;
    }
    float m = v[0];
    #pragma unroll
    for (int i = 1; i < 16; ++i) m = fmaxf(m, v[i]);
    float s = 0.f;
    #pragma unroll
    for (int i = 0; i < 16; ++i) { v[i] = expf(v[i] - m); s += v[i]; }
    const float inv = 1.f / s;
    #pragma unroll
    for (int i = 0; i < 4; ++i)
        p[i] = make_float4(v[i * 4 + 0] * inv, v[i * 4 + 1] * inv,
                           v[i * 4 + 2] * inv, v[i * 4 + 3] * inv);
}

// ---------------------------------------------------------------------------
// Multi-scale deformable sampling, head-pinned to XCDs.
// blockIdx.x = qgroup*8 + h  ->  consecutive blocks round-robin XCDs, so all
// blocks of head h land on XCD h; per-head v slice = 2.85 MB < 4 MiB L2.
// Block: 8 q x 32 d for one head. Writes outp as bf16.
// ---------------------------------------------------------------------------
__global__ __launch_bounds__(256) void msda_sample(
    const float* __restrict__ v, const float* __restrict__ off,
    const float* __restrict__ attnw, const float* __restrict__ ref,
    ushort* __restrict__ outp)
{
    const int h = blockIdx.x & 7;
    const int g = blockIdx.x >> 3;
    const int d = threadIdx.x & 31;
    const int q = g * 8 + (threadIdx.x >> 5);
    if (q >= LQ) return;

    const int Hs[4] = {100, 50, 25, 13};
    const int Ws[4] = {167, 84, 42, 21};
    const int starts[4] = {0, 16700, 20900, 21950};

    const float* offq = off + (size_t)q * CDIM + h * 32;   // 16 points * 2
    const float* aw   = attnw + (size_t)q * (NH * 16) + h * 16;
    const float* refq = ref + (size_t)q * (NL * 4);

    float acc = 0.f;

    #pragma unroll
    for (int l = 0; l < 4; ++l) {
        const float cx = refq[l * 4 + 0];
        const float cy = refq[l * 4 + 1];
        const float rw = refq[l * 4 + 2];
        const float rh = refq[l * 4 + 3];
        const int   W  = Ws[l];
        const int   H  = Hs[l];
        const float fW = (float)W;
        const float fH = (float)H;
        const float* vl = v + (size_t)starts[l] * CDIM + h * 32 + d;

        #pragma unroll
        for (int p = 0; p < 4; ++p) {
            const float ox  = offq[l * 8 + p * 2 + 0];
            const float oy  = offq[l * 8 + p * 2 + 1];
            const float wgt = aw[l * 4 + p];

            const float lx = cx + ((ox * 0.25f) * rw) * 0.5f;
            const float ly = cy + ((oy * 0.25f) * rh) * 0.5f;
            const float x = (2.f * lx) * 0.5f * fW - 0.5f + 0.f * (fW);  // = lx*fW - 0.5
            const float y = ly * fH - 0.5f;
            // note: grid=2*loc-1 then (g+1)/2*W-0.5 == loc*W-0.5

            const float x0f = floorf(x);
            const float y0f = floorf(y);
            const int x0 = (int)x0f;
            const int y0 = (int)y0f;
            const float wx1 = x - x0f, wy1 = y - y0f;
            const float wx0 = 1.f - wx1, wy0 = 1.f - wy1;

            const bool xv0 = (x0 >= 0) && (x0 < W);
            const bool xv1 = (x0 + 1 >= 0) && (x0 + 1 < W);
            const bool yv0 = (y0 >= 0) && (y0 < H);
            const bool yv1 = (y0 + 1 >= 0) && (y0 + 1 < H);

            float s = 0.f;
            if (yv0) {
                const float* row0 = vl + (size_t)(y0 * W) * CDIM;
                if (xv0) s += row0[(size_t)x0 * CDIM] * (wy0 * wx0);
                if (xv1) s += row0[(size_t)(x0 + 1) * CDIM] * (wy0 * wx1);
            }
            if (yv1) {
                const float* row1 = vl + (size_t)((y0 + 1) * W) * CDIM;
                if (xv0) s += row1[(size_t)x0 * CDIM] * (wy1 * wx0);
                if (xv1) s += row1[(size_t)(x0 + 1) * CDIM] * (wy1 * wx1);
            }
            acc += wgt * s;
        }
    }
    outp[(size_t)q * CDIM + h * 32 + d] = f2bf(acc);
}

// ---------------------------------------------------------------------------
extern "C" void kernel_launch(void* const* d_in, const int* in_sizes, int n_in,
                              void* d_out, int out_size, void* d_ws, size_t ws_size,
                              hipStream_t stream)
{
    const float* query  = (const float*)d_in[0];
    const float* ref    = (const float*)d_in[1];
    const float* value  = (const float*)d_in[2];
    const float* W_off  = (const float*)d_in[3];
    const float* b_off  = (const float*)d_in[4];
    const float* W_attn = (const float*)d_in[5];
    const float* b_attn = (const float*)d_in[6];
    const float* W_val  = (const float*)d_in[7];
    const float* b_val  = (const float*)d_in[8];
    const float* W_out  = (const float*)d_in[9];
    const float* b_out  = (const float*)d_in[10];
    float* out = (float*)d_out;

    char* p = (char*)d_ws;
    float*  v      = (float*)p;  p += (size_t)LQ * CDIM * 4;
    float*  off    = (float*)p;  p += (size_t)LQ * CDIM * 4;
    float*  attn   = (float*)p;  p += (size_t)LQ * 128 * 4;
    ushort* q_bf   = (ushort*)p; p += (size_t)LQ * CDIM * 2;  // aliased by outp
    ushort* val_bf = (ushort*)p; p += (size_t)LQ * CDIM * 2;
    ushort* Wt_val  = (ushort*)p; p += 65536 * 2;
    ushort* Wt_off  = (ushort*)p; p += 65536 * 2;
    ushort* Wt_out  = (ushort*)p; p += 65536 * 2;
    ushort* Wt_attn = (ushort*)p; p += 32768 * 2;
    ushort* outp = q_bf;   // safe: sampler runs after both query GEMMs

    const int n8 = LQ * CDIM / 8;   // 711136
    const int mblk = (LQ + 63) / 64;   // 348

    // 1. activations fp32 -> bf16
    convert_act<<<(2 * n8 + 255) / 256, 256, 0, stream>>>(
        (const float4*)query, (const float4*)value, q_bf, val_bf, n8);
    // 2. weights fp32 -> bf16 transposed [N][K]
    convert_wt<<<(229376 + 255) / 256, 256, 0, stream>>>(
        W_val, W_off, W_out, W_attn, Wt_val, Wt_off, Wt_out, Wt_attn);

    // 3. v = value @ W_val + b_val          (fp32 out)
    gemm_bf16<<<dim3(CDIM / 64, mblk), 256, 0, stream>>>(
        val_bf, Wt_val, b_val, v, LQ, CDIM);
    // 4. off = query @ W_off + b_off
    gemm_bf16<<<dim3(CDIM / 64, mblk), 256, 0, stream>>>(
        q_bf, Wt_off, b_off, off, LQ, CDIM);
    // 5. attn logits = query @ W_attn + b_attn
    gemm_bf16<<<dim3(128 / 64, mblk), 256, 0, stream>>>(
        q_bf, Wt_attn, b_attn, attn, LQ, 128);
    // 6. softmax over 16 per (q,h)
    softmax16<<<(LQ * NH + 255) / 256, 256, 0, stream>>>(attn, LQ * NH);
    // 7. head-pinned deformable sampling -> outp (bf16)
    const int qg = (LQ + 7) / 8;   // 2778
    msda_sample<<<qg * 8, 256, 0, stream>>>(v, off, attn, ref, outp);
    // 8. out = outp @ W_out + b_out
    gemm_bf16<<<dim3(CDIM / 64, mblk), 256, 0, stream>>>(
        outp, Wt_out, b_out, out, LQ, CDIM);
}

// Round 3
// 242.717 us; speedup vs baseline: 2.2369x; 1.5411x over previous
//
#include <hip/hip_runtime.h>
#include <math.h>

#define LQ 22223
#define NH 8
#define NL 4
#define NP 4
#define CDIM 256

typedef __attribute__((ext_vector_type(8))) short short8;
typedef __attribute__((ext_vector_type(4))) float f32x4;

__device__ __forceinline__ ushort f2bf(float f) {
    union { float f; unsigned u; } c; c.f = f;
    unsigned u = c.u;
    return (ushort)((u + 0x7fffu + ((u >> 16) & 1u)) >> 16);   // RNE
}

// ---------------------------------------------------------------------------
// Convert query & value fp32 -> bf16 (8 elems/thread)
// ---------------------------------------------------------------------------
__global__ __launch_bounds__(256) void convert_act(
    const float4* __restrict__ q, const float4* __restrict__ v,
    ushort* __restrict__ qb, ushort* __restrict__ vb, int n8each)
{
    int i = blockIdx.x * 256 + threadIdx.x;
    const float4* src; ushort* dst; int j;
    if (i < n8each) { src = q; dst = qb; j = i; }
    else if (i < 2 * n8each) { src = v; dst = vb; j = i - n8each; }
    else return;
    const float4 a = src[2 * j];
    const float4 b = src[2 * j + 1];
    short8 o;
    o[0] = (short)f2bf(a.x); o[1] = (short)f2bf(a.y);
    o[2] = (short)f2bf(a.z); o[3] = (short)f2bf(a.w);
    o[4] = (short)f2bf(b.x); o[5] = (short)f2bf(b.y);
    o[6] = (short)f2bf(b.z); o[7] = (short)f2bf(b.w);
    *reinterpret_cast<short8*>(dst + 8 * j) = o;
}

// ---------------------------------------------------------------------------
// Transpose+convert weights fp32 [K=256][N] -> bf16 [N][K].
// Wt_oa is W_off (rows 0..255) and W_attn (rows 256..383) concatenated so
// one N=384 GEMM computes both. Also builds the concatenated bias (384 fl).
// ---------------------------------------------------------------------------
__global__ __launch_bounds__(256) void convert_wt(
    const float* __restrict__ Wv, const float* __restrict__ Wo,
    const float* __restrict__ Wu, const float* __restrict__ Wa,
    const float* __restrict__ bo, const float* __restrict__ ba,
    ushort* __restrict__ Tv, ushort* __restrict__ Toa,
    ushort* __restrict__ Tu, float* __restrict__ bcat)
{
    int idx = blockIdx.x * 256 + threadIdx.x;
    if (idx >= 229376) {
        int b = idx - 229376;
        if (b < 384) bcat[b] = (b < 256) ? bo[b] : ba[b - 256];
        return;
    }
    const float* W; ushort* T; int N; int local;
    if      (idx < 65536)  { W = Wv; T = Tv;        N = 256; local = idx; }
    else if (idx < 131072) { W = Wo; T = Toa;       N = 256; local = idx - 65536; }
    else if (idx < 196608) { W = Wu; T = Tu;        N = 256; local = idx - 131072; }
    else                   { W = Wa; T = Toa + 65536; N = 128; local = idx - 196608; }
    int k = local & 255;
    int n = local >> 8;
    T[n * 256 + k] = f2bf(W[k * N + n]);
}

// ---------------------------------------------------------------------------
// bf16 MFMA GEMM: C[M,N] = A[M,256] @ Bt[N,256]^T + bias[N]   (fp32 out)
// 64x64 tile, BK=32, 256 threads = 4 waves, each wave 16 rows x 64 cols.
// ---------------------------------------------------------------------------
__global__ __launch_bounds__(256) void gemm_bf16(
    const ushort* __restrict__ A, const ushort* __restrict__ Bt,
    const float* __restrict__ bias, float* __restrict__ C,
    int M, int N)
{
    const int K = 256;
    __shared__ ushort As[64 * 40];
    __shared__ ushort Bs[64 * 40];

    const int tid = threadIdx.x;
    const int w = tid >> 6;
    const int l = tid & 63;
    const int bm = blockIdx.y * 64;
    const int bn = blockIdx.x * 64;

    const int r = tid >> 2;
    const int c = tid & 3;

    const int m_l  = (w << 4) + (l & 15);
    const int koff = (l >> 4) << 3;

    f32x4 acc[4] = {};

    for (int k0 = 0; k0 < K; k0 += 32) {
        short8 av = {0, 0, 0, 0, 0, 0, 0, 0};
        if (bm + r < M)
            av = *reinterpret_cast<const short8*>(A + (size_t)(bm + r) * K + k0 + c * 8);
        const short8 bv = *reinterpret_cast<const short8*>(
            Bt + (size_t)(bn + r) * K + k0 + c * 8);

        __syncthreads();
        *reinterpret_cast<short8*>(&As[r * 40 + c * 8]) = av;
        *reinterpret_cast<short8*>(&Bs[r * 40 + c * 8]) = bv;
        __syncthreads();

        const short8 af = *reinterpret_cast<const short8*>(&As[m_l * 40 + koff]);
        #pragma unroll
        for (int t = 0; t < 4; ++t) {
            const short8 bf = *reinterpret_cast<const short8*>(
                &Bs[(t * 16 + (l & 15)) * 40 + koff]);
            acc[t] = __builtin_amdgcn_mfma_f32_16x16x32_bf16(af, bf, acc[t], 0, 0, 0);
        }
    }

    const int row0 = bm + (w << 4) + ((l >> 4) << 2);
    #pragma unroll
    for (int t = 0; t < 4; ++t) {
        const int col = bn + t * 16 + (l & 15);
        const float bs = bias[col];
        #pragma unroll
        for (int i = 0; i < 4; ++i) {
            const int row = row0 + i;
            if (row < M) C[(size_t)row * N + col] = acc[t][i] + bs;
        }
    }
}

// ---------------------------------------------------------------------------
// In-place softmax over 16 logits per (q,h); logits live at
// base + q*384 + 256 + h*16 inside the fused off/attn output.
// ---------------------------------------------------------------------------
__global__ __launch_bounds__(256) void softmax16(float* __restrict__ offattn, int rows)
{
    const int r = blockIdx.x * 256 + threadIdx.x;
    if (r >= rows) return;
    const int q = r >> 3;
    const int h = r & 7;
    float4* p = reinterpret_cast<float4*>(offattn + (size_t)q * 384 + 256 + h * 16);
    float v[16];
    #pragma unroll
    for (int i = 0; i < 4; ++i) {
        const float4 f = p[i];
        v[i * 4 + 0] = f.x; v[i * 4 + 1] = f.y; v[i * 4 + 2] = f.z; v[i * 4 + 3] = f.w;
    }
    float m = v[0];
    #pragma unroll
    for (int i = 1; i < 16; ++i) m = fmaxf(m, v[i]);
    float s = 0.f;
    #pragma unroll
    for (int i = 0; i < 16; ++i) { v[i] = expf(v[i] - m); s += v[i]; }
    const float inv = 1.f / s;
    #pragma unroll
    for (int i = 0; i < 4; ++i)
        p[i] = make_float4(v[i * 4 + 0] * inv, v[i * 4 + 1] * inv,
                           v[i * 4 + 2] * inv, v[i * 4 + 3] * inv);
}

// ---------------------------------------------------------------------------
// Multi-scale deformable sampling, restructured:
//   block = 32 q x 8 lanes (float4 channels), one head; head-pinned to XCDs
//   via blockIdx.x = qg*8 + h.
// Phase 1: 512 (q,point) tasks -> corner offsets + folded weights in LDS.
//   LDS layout [p][qi] so phase-2 ds_read_b128 hits all 32 banks once.
// Phase 2: per (q, lane) gather 4 corners as float4, FMA with LDS weights.
// ---------------------------------------------------------------------------
__global__ __launch_bounds__(256) void msda_sample(
    const float* __restrict__ v, const float* __restrict__ offattn,
    const float* __restrict__ ref, ushort* __restrict__ outp)
{
    __shared__ int4   s_off[512];   // [p*32 + qi]
    __shared__ float4 s_wts[512];

    const int h = blockIdx.x & 7;
    const int qbase = (blockIdx.x >> 3) * 32;
    const int tid = threadIdx.x;

    const int Hs[4] = {100, 50, 25, 13};
    const int Ws[4] = {167, 84, 42, 21};
    const int starts[4] = {0, 16700, 20900, 21950};
    const int h32 = h * 32;

    // ---- Phase 1: coordinates & weights ----
    #pragma unroll
    for (int t2 = 0; t2 < 2; ++t2) {
        const int t = tid + t2 * 256;     // task id
        const int qi = t & 31;
        const int pi = t >> 5;            // 0..15
        const int q = qbase + qi;
        if (q < LQ) {
            const int l = pi >> 2;
            const int W = Ws[l], H = Hs[l];
            const float* refq = ref + (size_t)q * (NL * 4) + l * 4;
            const float cx = refq[0], cy = refq[1], rw = refq[2], rh = refq[3];
            const float* row = offattn + (size_t)q * 384;
            const float ox = row[h32 + pi * 2];
            const float oy = row[h32 + pi * 2 + 1];
            const float wgt = row[256 + h * 16 + pi];

            const float lx = cx + ox * 0.125f * rw;
            const float ly = cy + oy * 0.125f * rh;
            const float x = lx * (float)W - 0.5f;
            const float y = ly * (float)H - 0.5f;

            const float x0f = floorf(x);
            const float y0f = floorf(y);
            const int x0 = (int)x0f, y0 = (int)y0f;
            const float wx1 = x - x0f, wy1 = y - y0f;
            const float wx0 = 1.f - wx1, wy0 = 1.f - wy1;

            const bool xv0 = (x0 >= 0) && (x0 < W);
            const bool xv1 = (x0 + 1 >= 0) && (x0 + 1 < W);
            const bool yv0 = (y0 >= 0) && (y0 < H);
            const bool yv1 = (y0 + 1 >= 0) && (y0 + 1 < H);

            const int x0c = min(max(x0, 0), W - 1);
            const int x1c = min(max(x0 + 1, 0), W - 1);
            const int y0c = min(max(y0, 0), H - 1);
            const int y1c = min(max(y0 + 1, 0), H - 1);

            int4 ob;
            ob.x = ((starts[l] + y0c * W + x0c) << 8) + h32;
            ob.y = ((starts[l] + y0c * W + x1c) << 8) + h32;
            ob.z = ((starts[l] + y1c * W + x0c) << 8) + h32;
            ob.w = ((starts[l] + y1c * W + x1c) << 8) + h32;
            float4 wb;
            wb.x = (xv0 && yv0) ? wgt * wy0 * wx0 : 0.f;
            wb.y = (xv1 && yv0) ? wgt * wy0 * wx1 : 0.f;
            wb.z = (xv0 && yv1) ? wgt * wy1 * wx0 : 0.f;
            wb.w = (xv1 && yv1) ? wgt * wy1 * wx1 : 0.f;
            s_off[t] = ob;
            s_wts[t] = wb;
        }
    }
    __syncthreads();

    // ---- Phase 2: gather + accumulate ----
    const int qi = tid >> 3;          // 0..31
    const int dg = tid & 7;           // channel group (4 floats)
    const int q = qbase + qi;
    if (q >= LQ) return;

    f32x4 acc = {0.f, 0.f, 0.f, 0.f};
    const int d4 = dg * 4;

    #pragma unroll
    for (int p = 0; p < 16; ++p) {
        const int4   o = s_off[p * 32 + qi];
        const float4 w = s_wts[p * 32 + qi];
        const float4 c00 = *reinterpret_cast<const float4*>(v + o.x + d4);
        const float4 c01 = *reinterpret_cast<const float4*>(v + o.y + d4);
        const float4 c10 = *reinterpret_cast<const float4*>(v + o.z + d4);
        const float4 c11 = *reinterpret_cast<const float4*>(v + o.w + d4);
        acc[0] += w.x * c00.x + w.y * c01.x + w.z * c10.x + w.w * c11.x;
        acc[1] += w.x * c00.y + w.y * c01.y + w.z * c10.y + w.w * c11.y;
        acc[2] += w.x * c00.z + w.y * c01.z + w.z * c10.z + w.w * c11.z;
        acc[3] += w.x * c00.w + w.y * c01.w + w.z * c10.w + w.w * c11.w;
    }

    ushort4 o4;
    o4.x = f2bf(acc[0]); o4.y = f2bf(acc[1]);
    o4.z = f2bf(acc[2]); o4.w = f2bf(acc[3]);
    *reinterpret_cast<ushort4*>(outp + (size_t)q * CDIM + h32 + d4) = o4;
}

// ---------------------------------------------------------------------------
extern "C" void kernel_launch(void* const* d_in, const int* in_sizes, int n_in,
                              void* d_out, int out_size, void* d_ws, size_t ws_size,
                              hipStream_t stream)
{
    const float* query  = (const float*)d_in[0];
    const float* ref    = (const float*)d_in[1];
    const float* value  = (const float*)d_in[2];
    const float* W_off  = (const float*)d_in[3];
    const float* b_off  = (const float*)d_in[4];
    const float* W_attn = (const float*)d_in[5];
    const float* b_attn = (const float*)d_in[6];
    const float* W_val  = (const float*)d_in[7];
    const float* b_val  = (const float*)d_in[8];
    const float* W_out  = (const float*)d_in[9];
    const float* b_out  = (const float*)d_in[10];
    float* out = (float*)d_out;

    char* p = (char*)d_ws;
    float*  v       = (float*)p;  p += (size_t)LQ * CDIM * 4;
    float*  offattn = (float*)p;  p += (size_t)LQ * 384 * 4;
    ushort* q_bf    = (ushort*)p; p += (size_t)LQ * CDIM * 2;  // aliased by outp
    ushort* val_bf  = (ushort*)p; p += (size_t)LQ * CDIM * 2;
    ushort* Wt_val  = (ushort*)p; p += 65536 * 2;
    ushort* Wt_oa   = (ushort*)p; p += (65536 + 32768) * 2;    // off rows + attn rows
    ushort* Wt_out  = (ushort*)p; p += 65536 * 2;
    float*  bcat    = (float*)p;  p += 384 * 4;
    ushort* outp = q_bf;   // safe: sampler runs after the query GEMM

    const int n8 = LQ * CDIM / 8;
    const int mblk = (LQ + 63) / 64;   // 348

    convert_act<<<(2 * n8 + 255) / 256, 256, 0, stream>>>(
        (const float4*)query, (const float4*)value, q_bf, val_bf, n8);
    convert_wt<<<(229376 + 384 + 255) / 256, 256, 0, stream>>>(
        W_val, W_off, W_out, W_attn, b_off, b_attn, Wt_val, Wt_oa, Wt_out, bcat);

    // v = value @ W_val + b_val
    gemm_bf16<<<dim3(CDIM / 64, mblk), 256, 0, stream>>>(
        val_bf, Wt_val, b_val, v, LQ, CDIM);
    // offattn = query @ [W_off | W_attn] + [b_off | b_attn]   (N = 384)
    gemm_bf16<<<dim3(384 / 64, mblk), 256, 0, stream>>>(
        q_bf, Wt_oa, bcat, offattn, LQ, 384);
    // softmax over 16 per (q,h)
    softmax16<<<(LQ * NH + 255) / 256, 256, 0, stream>>>(offattn, LQ * NH);
    // deformable sampling -> outp (bf16)
    const int qg = (LQ + 31) / 32;    // 695
    msda_sample<<<qg * 8, 256, 0, stream>>>(v, offattn, ref, outp);
    // out = outp @ W_out + b_out
    gemm_bf16<<<dim3(CDIM / 64, mblk), 256, 0, stream>>>(
        outp, Wt_out, b_out, out, LQ, CDIM);
}

// Round 4
// 235.681 us; speedup vs baseline: 2.3036x; 1.0299x over previous
//
#include <hip/hip_runtime.h>
#include <math.h>

#define LQ 22223
#define NH 8
#define NL 4
#define NP 4
#define CDIM 256

typedef __attribute__((ext_vector_type(8))) short short8;
typedef __attribute__((ext_vector_type(4))) float f32x4;

__device__ __forceinline__ ushort f2bf(float f) {
    union { float f; unsigned u; } c; c.f = f;
    unsigned u = c.u;
    return (ushort)((u + 0x7fffu + ((u >> 16) & 1u)) >> 16);   // RNE
}
__device__ __forceinline__ float bflo(unsigned u) {
    union { unsigned u; float f; } c; c.u = u << 16; return c.f;
}
__device__ __forceinline__ float bfhi(unsigned u) {
    union { unsigned u; float f; } c; c.u = u & 0xffff0000u; return c.f;
}

// ---------------------------------------------------------------------------
// Convert query & value fp32 -> bf16 (8 elems/thread)
// ---------------------------------------------------------------------------
__global__ __launch_bounds__(256) void convert_act(
    const float4* __restrict__ q, const float4* __restrict__ v,
    ushort* __restrict__ qb, ushort* __restrict__ vb, int n8each)
{
    int i = blockIdx.x * 256 + threadIdx.x;
    const float4* src; ushort* dst; int j;
    if (i < n8each) { src = q; dst = qb; j = i; }
    else if (i < 2 * n8each) { src = v; dst = vb; j = i - n8each; }
    else return;
    const float4 a = src[2 * j];
    const float4 b = src[2 * j + 1];
    short8 o;
    o[0] = (short)f2bf(a.x); o[1] = (short)f2bf(a.y);
    o[2] = (short)f2bf(a.z); o[3] = (short)f2bf(a.w);
    o[4] = (short)f2bf(b.x); o[5] = (short)f2bf(b.y);
    o[6] = (short)f2bf(b.z); o[7] = (short)f2bf(b.w);
    *reinterpret_cast<short8*>(dst + 8 * j) = o;
}

// ---------------------------------------------------------------------------
// Transpose+convert weights fp32 [K=256][N] -> bf16 [N][K].
// Wt_oa = concat(W_off rows, W_attn rows) so one N=384 GEMM does both.
// ---------------------------------------------------------------------------
__global__ __launch_bounds__(256) void convert_wt(
    const float* __restrict__ Wv, const float* __restrict__ Wo,
    const float* __restrict__ Wu, const float* __restrict__ Wa,
    const float* __restrict__ bo, const float* __restrict__ ba,
    ushort* __restrict__ Tv, ushort* __restrict__ Toa,
    ushort* __restrict__ Tu, float* __restrict__ bcat)
{
    int idx = blockIdx.x * 256 + threadIdx.x;
    if (idx >= 229376) {
        int b = idx - 229376;
        if (b < 384) bcat[b] = (b < 256) ? bo[b] : ba[b - 256];
        return;
    }
    const float* W; ushort* T; int N; int local;
    if      (idx < 65536)  { W = Wv; T = Tv;          N = 256; local = idx; }
    else if (idx < 131072) { W = Wo; T = Toa;         N = 256; local = idx - 65536; }
    else if (idx < 196608) { W = Wu; T = Tu;          N = 256; local = idx - 131072; }
    else                   { W = Wa; T = Toa + 65536; N = 128; local = idx - 196608; }
    int k = local & 255;
    int n = local >> 8;
    T[n * 256 + k] = f2bf(W[k * N + n]);
}

// ---------------------------------------------------------------------------
// bf16 MFMA GEMM: C[M,N] = A[M,256] @ Bt[N,256]^T + bias[N]
// 64x64 tile, BK=32, 256 threads = 4 waves. OutT = float or ushort (bf16).
// ---------------------------------------------------------------------------
template <typename OutT>
__global__ __launch_bounds__(256) void gemm_bf16(
    const ushort* __restrict__ A, const ushort* __restrict__ Bt,
    const float* __restrict__ bias, OutT* __restrict__ C,
    int M, int N)
{
    const int K = 256;
    __shared__ ushort As[64 * 40];
    __shared__ ushort Bs[64 * 40];

    const int tid = threadIdx.x;
    const int w = tid >> 6;
    const int l = tid & 63;
    const int bm = blockIdx.y * 64;
    const int bn = blockIdx.x * 64;

    const int r = tid >> 2;
    const int c = tid & 3;

    const int m_l  = (w << 4) + (l & 15);
    const int koff = (l >> 4) << 3;

    f32x4 acc[4] = {};

    for (int k0 = 0; k0 < K; k0 += 32) {
        short8 av = {0, 0, 0, 0, 0, 0, 0, 0};
        if (bm + r < M)
            av = *reinterpret_cast<const short8*>(A + (size_t)(bm + r) * K + k0 + c * 8);
        const short8 bv = *reinterpret_cast<const short8*>(
            Bt + (size_t)(bn + r) * K + k0 + c * 8);

        __syncthreads();
        *reinterpret_cast<short8*>(&As[r * 40 + c * 8]) = av;
        *reinterpret_cast<short8*>(&Bs[r * 40 + c * 8]) = bv;
        __syncthreads();

        const short8 af = *reinterpret_cast<const short8*>(&As[m_l * 40 + koff]);
        #pragma unroll
        for (int t = 0; t < 4; ++t) {
            const short8 bf = *reinterpret_cast<const short8*>(
                &Bs[(t * 16 + (l & 15)) * 40 + koff]);
            acc[t] = __builtin_amdgcn_mfma_f32_16x16x32_bf16(af, bf, acc[t], 0, 0, 0);
        }
    }

    const int row0 = bm + (w << 4) + ((l >> 4) << 2);
    #pragma unroll
    for (int t = 0; t < 4; ++t) {
        const int col = bn + t * 16 + (l & 15);
        const float bs = bias[col];
        #pragma unroll
        for (int i = 0; i < 4; ++i) {
            const int row = row0 + i;
            if (row < M) {
                const float o = acc[t][i] + bs;
                if constexpr (sizeof(OutT) == 2)
                    C[(size_t)row * N + col] = (OutT)f2bf(o);
                else
                    C[(size_t)row * N + col] = (OutT)o;
            }
        }
    }
}

// ---------------------------------------------------------------------------
// In-place softmax over 16 logits per (q,h) at offattn + q*384 + 256 + h*16.
// ---------------------------------------------------------------------------
__global__ __launch_bounds__(256) void softmax16(float* __restrict__ offattn, int rows)
{
    const int r = blockIdx.x * 256 + threadIdx.x;
    if (r >= rows) return;
    const int q = r >> 3;
    const int h = r & 7;
    float4* p = reinterpret_cast<float4*>(offattn + (size_t)q * 384 + 256 + h * 16);
    float v[16];
    #pragma unroll
    for (int i = 0; i < 4; ++i) {
        const float4 f = p[i];
        v[i * 4 + 0] = f.x; v[i * 4 + 1] = f.y; v[i * 4 + 2] = f.z; v[i * 4 + 3] = f.w;
    }
    float m = v[0];
    #pragma unroll
    for (int i = 1; i < 16; ++i) m = fmaxf(m, v[i]);
    float s = 0.f;
    #pragma unroll
    for (int i = 0; i < 16; ++i) { v[i] = expf(v[i] - m); s += v[i]; }
    const float inv = 1.f / s;
    #pragma unroll
    for (int i = 0; i < 4; ++i)
        p[i] = make_float4(v[i * 4 + 0] * inv, v[i * 4 + 1] * inv,
                           v[i * 4 + 2] * inv, v[i * 4 + 3] * inv);
}

// ---------------------------------------------------------------------------
// Multi-scale deformable sampling over bf16 value.
//   block = 64 q x 4 lanes (8 bf16 channels each), one head.
//   blockIdx.x = qg*8 + h  -> head-pinned to XCDs (per-head slice 1.42 MB).
// Phase 1: 1024 (q,point) tasks -> corner element-offsets + folded weights
//   in LDS, layout [p][qi].
// Phase 2: per (q,lane): 4 corners x dwordx4 (8 bf16), manually 2-point
//   software-pipelined so ~8 loads stay in flight per wave.
// ---------------------------------------------------------------------------
__global__ __launch_bounds__(256) void msda_sample(
    const ushort* __restrict__ v, const float* __restrict__ offattn,
    const float* __restrict__ ref, ushort* __restrict__ outp)
{
    __shared__ int4   s_off[1024];   // [p*64 + qi], element offsets into v
    __shared__ float4 s_wts[1024];

    const int h = blockIdx.x & 7;
    const int qbase = (blockIdx.x >> 3) * 64;
    const int tid = threadIdx.x;

    const int Hs[4] = {100, 50, 25, 13};
    const int Ws[4] = {167, 84, 42, 21};
    const int starts[4] = {0, 16700, 20900, 21950};
    const int h32 = h * 32;

    // ---- Phase 1 ----
    #pragma unroll
    for (int t2 = 0; t2 < 4; ++t2) {
        const int t = t2 * 256 + tid;     // = pi*64 + qi
        const int qi = t & 63;
        const int pi = t >> 6;            // 0..15
        const int q = qbase + qi;
        if (q < LQ) {
            const int l = pi >> 2;
            const int W = Ws[l], H = Hs[l];
            const float* refq = ref + (size_t)q * (NL * 4) + l * 4;
            const float cx = refq[0], cy = refq[1], rw = refq[2], rh = refq[3];
            const float* row = offattn + (size_t)q * 384;
            const float ox = row[h32 + pi * 2];
            const float oy = row[h32 + pi * 2 + 1];
            const float wgt = row[256 + h * 16 + pi];

            const float lx = cx + ox * 0.125f * rw;
            const float ly = cy + oy * 0.125f * rh;
            const float x = lx * (float)W - 0.5f;
            const float y = ly * (float)H - 0.5f;

            const float x0f = floorf(x);
            const float y0f = floorf(y);
            const int x0 = (int)x0f, y0 = (int)y0f;
            const float wx1 = x - x0f, wy1 = y - y0f;
            const float wx0 = 1.f - wx1, wy0 = 1.f - wy1;

            const bool xv0 = (x0 >= 0) && (x0 < W);
            const bool xv1 = (x0 + 1 >= 0) && (x0 + 1 < W);
            const bool yv0 = (y0 >= 0) && (y0 < H);
            const bool yv1 = (y0 + 1 >= 0) && (y0 + 1 < H);

            const int x0c = min(max(x0, 0), W - 1);
            const int x1c = min(max(x0 + 1, 0), W - 1);
            const int y0c = min(max(y0, 0), H - 1);
            const int y1c = min(max(y0 + 1, 0), H - 1);

            int4 ob;
            ob.x = ((starts[l] + y0c * W + x0c) << 8) + h32;
            ob.y = ((starts[l] + y0c * W + x1c) << 8) + h32;
            ob.z = ((starts[l] + y1c * W + x0c) << 8) + h32;
            ob.w = ((starts[l] + y1c * W + x1c) << 8) + h32;
            float4 wb;
            wb.x = (xv0 && yv0) ? wgt * wy0 * wx0 : 0.f;
            wb.y = (xv1 && yv0) ? wgt * wy0 * wx1 : 0.f;
            wb.z = (xv0 && yv1) ? wgt * wy1 * wx0 : 0.f;
            wb.w = (xv1 && yv1) ? wgt * wy1 * wx1 : 0.f;
            s_off[t] = ob;
            s_wts[t] = wb;
        }
    }
    __syncthreads();

    // ---- Phase 2 ----
    const int qi = tid >> 2;          // 0..63
    const int dg = tid & 3;           // channel group (8 bf16)
    const int q = qbase + qi;
    if (q >= LQ) return;
    const int d8 = dg * 8;

    float acc[8] = {};

    int4   o = s_off[qi];
    float4 w = s_wts[qi];
    uint4 a0 = *reinterpret_cast<const uint4*>(v + o.x + d8);
    uint4 a1 = *reinterpret_cast<const uint4*>(v + o.y + d8);
    uint4 a2 = *reinterpret_cast<const uint4*>(v + o.z + d8);
    uint4 a3 = *reinterpret_cast<const uint4*>(v + o.w + d8);

    #pragma unroll
    for (int p = 0; p < 16; ++p) {
        uint4 b0, b1, b2, b3; float4 wn;
        if (p < 15) {
            const int4 on = s_off[(p + 1) * 64 + qi];
            wn = s_wts[(p + 1) * 64 + qi];
            b0 = *reinterpret_cast<const uint4*>(v + on.x + d8);
            b1 = *reinterpret_cast<const uint4*>(v + on.y + d8);
            b2 = *reinterpret_cast<const uint4*>(v + on.z + d8);
            b3 = *reinterpret_cast<const uint4*>(v + on.w + d8);
        }
        const unsigned u0[4] = {a0.x, a0.y, a0.z, a0.w};
        const unsigned u1[4] = {a1.x, a1.y, a1.z, a1.w};
        const unsigned u2[4] = {a2.x, a2.y, a2.z, a2.w};
        const unsigned u3[4] = {a3.x, a3.y, a3.z, a3.w};
        #pragma unroll
        for (int j = 0; j < 4; ++j) {
            acc[2 * j]     += w.x * bflo(u0[j]) + w.y * bflo(u1[j])
                            + w.z * bflo(u2[j]) + w.w * bflo(u3[j]);
            acc[2 * j + 1] += w.x * bfhi(u0[j]) + w.y * bfhi(u1[j])
                            + w.z * bfhi(u2[j]) + w.w * bfhi(u3[j]);
        }
        a0 = b0; a1 = b1; a2 = b2; a3 = b3; w = wn;
    }

    short8 o8;
    #pragma unroll
    for (int j = 0; j < 8; ++j) o8[j] = (short)f2bf(acc[j]);
    *reinterpret_cast<short8*>(outp + (size_t)q * CDIM + h32 + d8) = o8;
}

// ---------------------------------------------------------------------------
extern "C" void kernel_launch(void* const* d_in, const int* in_sizes, int n_in,
                              void* d_out, int out_size, void* d_ws, size_t ws_size,
                              hipStream_t stream)
{
    const float* query  = (const float*)d_in[0];
    const float* ref    = (const float*)d_in[1];
    const float* value  = (const float*)d_in[2];
    const float* W_off  = (const float*)d_in[3];
    const float* b_off  = (const float*)d_in[4];
    const float* W_attn = (const float*)d_in[5];
    const float* b_attn = (const float*)d_in[6];
    const float* W_val  = (const float*)d_in[7];
    const float* b_val  = (const float*)d_in[8];
    const float* W_out  = (const float*)d_in[9];
    const float* b_out  = (const float*)d_in[10];
    float* out = (float*)d_out;

    char* p = (char*)d_ws;
    ushort* v_bf    = (ushort*)p; p += (size_t)LQ * CDIM * 2;   // bf16 value'
    float*  offattn = (float*)p;  p += (size_t)LQ * 384 * 4;
    ushort* q_bf    = (ushort*)p; p += (size_t)LQ * CDIM * 2;   // aliased by outp
    ushort* val_bf  = (ushort*)p; p += (size_t)LQ * CDIM * 2;
    ushort* Wt_val  = (ushort*)p; p += 65536 * 2;
    ushort* Wt_oa   = (ushort*)p; p += (65536 + 32768) * 2;
    ushort* Wt_out  = (ushort*)p; p += 65536 * 2;
    float*  bcat    = (float*)p;  p += 384 * 4;
    ushort* outp = q_bf;   // safe: sampler runs after the offattn GEMM

    const int n8 = LQ * CDIM / 8;
    const int mblk = (LQ + 63) / 64;   // 348

    convert_act<<<(2 * n8 + 255) / 256, 256, 0, stream>>>(
        (const float4*)query, (const float4*)value, q_bf, val_bf, n8);
    convert_wt<<<(229376 + 384 + 255) / 256, 256, 0, stream>>>(
        W_val, W_off, W_out, W_attn, b_off, b_attn, Wt_val, Wt_oa, Wt_out, bcat);

    // v_bf = bf16(value @ W_val + b_val)   (fused epilogue convert)
    gemm_bf16<ushort><<<dim3(CDIM / 64, mblk), 256, 0, stream>>>(
        val_bf, Wt_val, b_val, v_bf, LQ, CDIM);
    // offattn = query @ [W_off | W_attn] + [b_off | b_attn]   (N=384, fp32)
    gemm_bf16<float><<<dim3(384 / 64, mblk), 256, 0, stream>>>(
        q_bf, Wt_oa, bcat, offattn, LQ, 384);
    // softmax over 16 per (q,h)
    softmax16<<<(LQ * NH + 255) / 256, 256, 0, stream>>>(offattn, LQ * NH);
    // deformable sampling (bf16 gathers) -> outp (bf16)
    const int qg = (LQ + 63) / 64;    // 348
    msda_sample<<<qg * 8, 256, 0, stream>>>(v_bf, offattn, ref, outp);
    // out = outp @ W_out + b_out
    gemm_bf16<float><<<dim3(CDIM / 64, mblk), 256, 0, stream>>>(
        outp, Wt_out, b_out, out, LQ, CDIM);
}